// Round 10
// baseline (405.764 us; speedup 1.0000x reference)
//
#include <hip/hip_runtime.h>

#define NA 5
#define LL 500
#define DD 300
#define H1 10
#define H2 50
#define NB 256
#define ADS 11   // LDS row stride (odd -> conflict-free column access)

// ---------------- split path ----------------
// k_proj: grid = 2*256*2 (side,b,ch-half) x 512 thr. Thread = position l,
// 25 channels in regs (rounds-6/7 cs-split chains, bitwise-exact). No LDS,
// no barriers. adoc goes to global ws [2*256][500][50].
// k_attn: one wave per (side,b,aspect); stages 500x10 stripe in LDS and
// runs the round-9 logits/softmax/weighted-sum chains verbatim.

__global__ __launch_bounds__(512, 1)
void k_proj(const int* __restrict__ Uids, const int* __restrict__ Iids,
            const int* __restrict__ Udocs, const int* __restrict__ Idocs,
            const float* __restrict__ Wemb,
            const float* __restrict__ AP,   // [A][D][H1]
            float* __restrict__ adocG)      // [2*NB][LL][50]
{
    const int tid  = threadIdx.x;
    const int bid  = blockIdx.x;
    const int half = bid & 1;          // channel half: 0 -> c0..24, 1 -> c25..49
    const int sb   = bid >> 1;         // side*NB + b
    const int side = sb >> 8;
    const int b    = sb & 255;

    const int* ids  = side ? Iids : Uids;
    const int* docs = side ? Idocs : Udocs;
    const int uid = ids[b];
    const int* doc = docs + (long)uid * LL;

    if (tid < LL) {
        const int tok = doc[tid];
        float acc[25];
        #pragma unroll
        for (int c = 0; c < 25; ++c) acc[c] = 0.f;

        const float4* e4 = (const float4*)(Wemb + (long)tok * DD);
        float4 e0 = e4[0];
        float4 e1 = e4[1];
        for (int db = 0; db < 75; ++db) {
            float4 e2 = e1;
            if (db < 73) e2 = e4[db + 2];
            const float ev0 = e0.x, ev1 = e0.y, ev2 = e0.z, ev3 = e0.w;
            const int d0 = db * 4;
            if (half == 0) {
                #pragma unroll
                for (int a_ = 0; a_ < 3; ++a_) {
                    const float* wp = AP + a_ * (DD * H1) + d0 * H1;  // uniform -> s_load
                    const int hn = (a_ == 2) ? 5 : H1;
                    #pragma unroll
                    for (int h = 0; h < H1; ++h) {
                        if (h < hn)
                            acc[a_ * H1 + h] += ev0 * wp[h] + ev1 * wp[H1 + h]
                                              + ev2 * wp[2 * H1 + h] + ev3 * wp[3 * H1 + h];
                    }
                }
            } else {
                #pragma unroll
                for (int a_ = 2; a_ < 5; ++a_) {
                    const float* wp = AP + a_ * (DD * H1) + d0 * H1;
                    const int h0 = (a_ == 2) ? 5 : 0;
                    #pragma unroll
                    for (int h = 0; h < H1; ++h) {
                        if (h >= h0)
                            acc[a_ * H1 + h - 25] += ev0 * wp[h] + ev1 * wp[H1 + h]
                                                   + ev2 * wp[2 * H1 + h] + ev3 * wp[3 * H1 + h];
                    }
                }
            }
            e0 = e1; e1 = e2;
        }

        float* out = adocG + ((long)sb * LL + tid) * 50 + half * 25;
        #pragma unroll
        for (int c = 0; c < 25; ++c) out[c] = acc[c];
    }
}

__global__ __launch_bounds__(64)
void k_attn(const float* __restrict__ adocG,
            const float* __restrict__ AE,   // [A][30]
            float* __restrict__ Rep)        // [2][NB][A][H1]
{
    __shared__ float stripe[LL][ADS];
    __shared__ float lg[LL];

    const int bid  = blockIdx.x;       // sb*NA + a
    const int a_   = bid % NA;
    const int sb   = bid / NA;
    const int lane = threadIdx.x;

    for (int l = lane; l < LL; l += 64) {
        const float* src = adocG + ((long)sb * LL + l) * 50 + a_ * H1;
        #pragma unroll
        for (int h = 0; h < H1; ++h) stripe[l][h] = src[h];
    }
    __syncthreads();

    // window logits (round-9 exact chain, strided by 64)
    const float* aerow = AE + a_ * 30;   // uniform -> s_load
    for (int l = lane; l < LL; l += 64) {
        float s = 0.f;
        if (l > 0) {
            const float* ad = &stripe[l - 1][0];
            #pragma unroll
            for (int h = 0; h < H1; ++h) s += ad[h] * aerow[h];
        }
        {
            const float* ad = &stripe[l][0];
            #pragma unroll
            for (int h = 0; h < H1; ++h) s += ad[h] * aerow[H1 + h];
        }
        if (l < LL - 1) {
            const float* ad = &stripe[l + 1][0];
            #pragma unroll
            for (int h = 0; h < H1; ++h) s += ad[h] * aerow[2 * H1 + h];
        }
        lg[l] = s;
    }
    __syncthreads();

    // softmax over L + weighted sum (round-9 exact reduction)
    float mx = -1e30f;
    for (int p = lane; p < LL; p += 64) mx = fmaxf(mx, lg[p]);
    #pragma unroll
    for (int o = 32; o; o >>= 1) mx = fmaxf(mx, __shfl_xor(mx, o, 64));
    float sum = 0.f;
    for (int p = lane; p < LL; p += 64) {
        float pr = expf(lg[p] - mx);
        lg[p] = pr;
        sum += pr;
    }
    #pragma unroll
    for (int o = 32; o; o >>= 1) sum += __shfl_xor(sum, o, 64);
    float r[H1];
    #pragma unroll
    for (int h = 0; h < H1; ++h) r[h] = 0.f;
    for (int p = lane; p < LL; p += 64) {
        const float pr = lg[p];
        const float* ad = &stripe[p][0];
        #pragma unroll
        for (int h = 0; h < H1; ++h) r[h] += pr * ad[h];
    }
    #pragma unroll
    for (int h = 0; h < H1; ++h) {
        #pragma unroll
        for (int o = 32; o; o >>= 1) r[h] += __shfl_xor(r[h], o, 64);
    }
    if (lane == 0) {
        const float inv = 1.f / sum;
        float* out = Rep + ((long)sb * NA + a_) * H1;
        #pragma unroll
        for (int h = 0; h < H1; ++h) out[h] = r[h] * inv;
    }
}

// ---------------- fallback fused path (round 9, 167 us) ----------------
__global__ __launch_bounds__(512, 1)
void k_aspect(const int* __restrict__ Uids, const int* __restrict__ Iids,
              const int* __restrict__ Udocs, const int* __restrict__ Idocs,
              const float* __restrict__ Wemb,
              const float* __restrict__ AE,
              const float* __restrict__ AP,
              float* __restrict__ Rep)
{
    __shared__ int   toks[LL];
    __shared__ float adoc[LL][ADS];
    __shared__ float lg[LL];

    const int tid  = threadIdx.x;
    const int bid  = blockIdx.x;
    const int side = bid >> 8;
    const int b    = bid & 255;

    const int* ids  = side ? Iids : Uids;
    const int* docs = side ? Idocs : Udocs;

    const int uid = ids[b];
    const int* doc = docs + (long)uid * LL;
    for (int i = tid; i < LL; i += 512) toks[i] = doc[i];
    __syncthreads();

    float acc[NA * H1];
    #pragma unroll
    for (int c = 0; c < NA * H1; ++c) acc[c] = 0.f;

    if (tid < LL) {
        const float4* e4 = (const float4*)(Wemb + (long)toks[tid] * DD);
        float4 e = e4[0];
        for (int db = 0; db < 75; ++db) {
            float4 en;
            if (db < 74) en = e4[db + 1]; else en = e;
            const float ev0 = e.x, ev1 = e.y, ev2 = e.z, ev3 = e.w;
            const int d0 = db * 4;
            #pragma unroll
            for (int a_ = 0; a_ < NA; ++a_) {
                const float* wp = AP + a_ * (DD * H1) + d0 * H1;
                #pragma unroll
                for (int h = 0; h < H1; ++h) {
                    acc[a_ * H1 + h] += ev0 * wp[h] + ev1 * wp[H1 + h]
                                      + ev2 * wp[2 * H1 + h] + ev3 * wp[3 * H1 + h];
                }
            }
            e = en;
        }
    }

    #pragma unroll
    for (int a_ = 0; a_ < NA; ++a_) {
        if (tid < LL) {
            #pragma unroll
            for (int h = 0; h < H1; ++h) adoc[tid][h] = acc[a_ * H1 + h];
        }
        __syncthreads();

        if (tid < LL) {
            const float* aerow = AE + a_ * 30;
            float s = 0.f;
            if (tid > 0) {
                const float* ad = &adoc[tid - 1][0];
                #pragma unroll
                for (int h = 0; h < H1; ++h) s += ad[h] * aerow[h];
            }
            {
                const float* ad = &adoc[tid][0];
                #pragma unroll
                for (int h = 0; h < H1; ++h) s += ad[h] * aerow[H1 + h];
            }
            if (tid < LL - 1) {
                const float* ad = &adoc[tid + 1][0];
                #pragma unroll
                for (int h = 0; h < H1; ++h) s += ad[h] * aerow[2 * H1 + h];
            }
            lg[tid] = s;
        }
        __syncthreads();

        if (tid < 64) {
            const int lane = tid;
            float mx = -1e30f;
            for (int p = lane; p < LL; p += 64) mx = fmaxf(mx, lg[p]);
            #pragma unroll
            for (int o = 32; o; o >>= 1) mx = fmaxf(mx, __shfl_xor(mx, o, 64));
            float sum = 0.f;
            for (int p = lane; p < LL; p += 64) {
                float pr = expf(lg[p] - mx);
                lg[p] = pr;
                sum += pr;
            }
            #pragma unroll
            for (int o = 32; o; o >>= 1) sum += __shfl_xor(sum, o, 64);
            float r[H1];
            #pragma unroll
            for (int h = 0; h < H1; ++h) r[h] = 0.f;
            for (int p = lane; p < LL; p += 64) {
                const float pr = lg[p];
                const float* ad = &adoc[p][0];
                #pragma unroll
                for (int h = 0; h < H1; ++h) r[h] += pr * ad[h];
            }
            #pragma unroll
            for (int h = 0; h < H1; ++h) {
                #pragma unroll
                for (int o = 32; o; o >>= 1) r[h] += __shfl_xor(r[h], o, 64);
            }
            if (lane == 0) {
                const float inv = 1.f / sum;
                float* out = Rep + (((long)side * NB + b) * NA + a_) * H1;
                #pragma unroll
                for (int h = 0; h < H1; ++h) out[h] = r[h] * inv;
            }
        }
        __syncthreads();
    }
}

__global__ __launch_bounds__(64)
void k_final(const float* __restrict__ Rep, const int* __restrict__ Uids,
             const int* __restrict__ Iids, const float* __restrict__ M,
             const float* __restrict__ Uproj, const float* __restrict__ Uw,
             const float* __restrict__ Iproj, const float* __restrict__ Iw,
             const float* __restrict__ Bu, const float* __restrict__ Bi,
             const float* __restrict__ Bg, float* __restrict__ out)
{
    __shared__ float Ud[50], Idd[50], tmp[50], aff[25];
    const int b = blockIdx.x, lane = threadIdx.x;
    if (lane < 50) {
        Ud[lane]  = Rep[(long)b * 50 + lane];
        Idd[lane] = Rep[(long)NB * 50 + (long)b * 50 + lane];
    }
    __syncthreads();
    if (lane < 50) {  // tmp[c][h] = sum_k M[h][k] * Id[c][k]
        const int c = lane / 10, h = lane % 10;
        float t = 0.f;
        #pragma unroll
        for (int k = 0; k < 10; ++k) t += M[h * 10 + k] * Idd[c * 10 + k];
        tmp[lane] = t;
    }
    __syncthreads();
    if (lane < 25) {  // aff[a][c] = relu(sum_h Ud[a][h] * tmp[c][h])
        const int a_ = lane / 5, c = lane % 5;
        float s = 0.f;
        #pragma unroll
        for (int h = 0; h < 10; ++h) s += Ud[a_ * 10 + h] * tmp[c * 10 + h];
        aff[lane] = fmaxf(s, 0.f);
    }
    __syncthreads();

    float hu1[5], hi1[5], tu[5], ti[5];
    if (lane < 50) {
        #pragma unroll
        for (int a_ = 0; a_ < 5; ++a_) {
            float su = 0.f, si = 0.f;
            #pragma unroll
            for (int h = 0; h < 10; ++h) {
                su += Uproj[lane * 10 + h] * Ud[a_ * 10 + h];
                si += Iproj[lane * 10 + h] * Idd[a_ * 10 + h];
            }
            hu1[a_] = su; hi1[a_] = si;
        }
    } else {
        #pragma unroll
        for (int a_ = 0; a_ < 5; ++a_) { hu1[a_] = 0.f; hi1[a_] = 0.f; }
    }
    const float uw = (lane < 50) ? Uw[lane] : 0.f;
    const float iw = (lane < 50) ? Iw[lane] : 0.f;
    #pragma unroll
    for (int a_ = 0; a_ < 5; ++a_) {
        float hu = hu1[a_], hi = hi1[a_];
        #pragma unroll
        for (int c = 0; c < 5; ++c) {
            hu += hi1[c] * aff[a_ * 5 + c];
            hi += hu1[c] * aff[c * 5 + a_];
        }
        tu[a_] = uw * fmaxf(hu, 0.f);
        ti[a_] = iw * fmaxf(hi, 0.f);
    }
    #pragma unroll
    for (int a_ = 0; a_ < 5; ++a_) {
        #pragma unroll
        for (int o = 32; o; o >>= 1) {
            tu[a_] += __shfl_xor(tu[a_], o, 64);
            ti[a_] += __shfl_xor(ti[a_], o, 64);
        }
    }
    if (lane == 0) {
        float mu = tu[0], mi = ti[0];
        #pragma unroll
        for (int a_ = 1; a_ < 5; ++a_) { mu = fmaxf(mu, tu[a_]); mi = fmaxf(mi, ti[a_]); }
        float eu[5], ei[5], su = 0.f, si = 0.f;
        #pragma unroll
        for (int a_ = 0; a_ < 5; ++a_) {
            eu[a_] = expf(tu[a_] - mu); su += eu[a_];
            ei[a_] = expf(ti[a_] - mi); si += ei[a_];
        }
        float R = 0.f;
        #pragma unroll
        for (int a_ = 0; a_ < 5; ++a_) {
            float ar = 0.f;
            #pragma unroll
            for (int h = 0; h < 10; ++h) ar += Ud[a_ * 10 + h] * Idd[a_ * 10 + h];
            R += (eu[a_] / su) * (ei[a_] / si) * ar;
        }
        R += Bu[Uids[b]] + Bi[Iids[b]] + Bg[0];
        out[b] = R;
    }
}

extern "C" void kernel_launch(void* const* d_in, const int* in_sizes, int n_in,
                              void* d_out, int out_size, void* d_ws, size_t ws_size,
                              hipStream_t stream)
{
    const int*   Uids  = (const int*)d_in[0];
    const int*   Iids  = (const int*)d_in[1];
    const int*   Udocs = (const int*)d_in[2];
    const int*   Idocs = (const int*)d_in[3];
    const float* Wemb  = (const float*)d_in[4];
    const float* AE    = (const float*)d_in[5];
    const float* AP    = (const float*)d_in[6];
    const float* M     = (const float*)d_in[7];
    const float* Uproj = (const float*)d_in[8];
    const float* Uw    = (const float*)d_in[9];
    const float* Iproj = (const float*)d_in[10];
    const float* Iw    = (const float*)d_in[11];
    const float* Bu    = (const float*)d_in[12];
    const float* Bi    = (const float*)d_in[13];
    const float* Bg    = (const float*)d_in[14];

    float* Rep = (float*)d_ws;                              // 102400 B
    float* out = (float*)d_out;
    const size_t REP_BYTES  = (size_t)2 * NB * NA * H1 * 4;
    const size_t ADOC_BYTES = (size_t)2 * NB * LL * 50 * 4; // 51.2 MB
    if (ws_size >= REP_BYTES + ADOC_BYTES) {
        float* adocG = (float*)((char*)d_ws + REP_BYTES);
        k_proj<<<2 * NB * 2, 512, 0, stream>>>(Uids, Iids, Udocs, Idocs, Wemb, AP, adocG);
        k_attn<<<2 * NB * NA, 64, 0, stream>>>(adocG, AE, Rep);
    } else {
        k_aspect<<<2 * NB, 512, 0, stream>>>(Uids, Iids, Udocs, Idocs, Wemb, AE, AP, Rep);
    }
    k_final<<<NB, 64, 0, stream>>>(Rep, Uids, Iids, M, Uproj, Uw, Iproj, Iw, Bu, Bi, Bg, out);
}

// Round 11
// 165.494 us; speedup vs baseline: 2.4518x; 2.4518x over previous
//
#include <hip/hip_runtime.h>

#define NA 5
#define LL 500
#define DD 300
#define H1 10
#define H2 50
#define NB 256
#define ADS 11   // adoc LDS row stride (odd -> conflict-free column access)

// One block per (side, batch): grid = 512, 512 threads, thread = position,
// all 50 channels in registers (AGPR-backed; round-9 proven no-spill at
// (512,1)). Aspect-at-a-time LDS staging (26 KB). Round-11 changes vs
// round 9: 2-deep float4 prefetch in the gather K-loop (latency hiding;
// load-order only -> bitwise identical) and direct doc[tid] read (no toks
// LDS, one less barrier). All FP chains verbatim from round 9 (absmax 0.0).

__global__ __launch_bounds__(512, 1)
void k_aspect(const int* __restrict__ Uids, const int* __restrict__ Iids,
              const int* __restrict__ Udocs, const int* __restrict__ Idocs,
              const float* __restrict__ Wemb,
              const float* __restrict__ AE,   // [A][30]
              const float* __restrict__ AP,   // [A][D][H1]
              float* __restrict__ Rep)        // [2][B][A][H1]
{
    __shared__ float adoc[LL][ADS];
    __shared__ float lg[LL];

    const int tid  = threadIdx.x;
    const int bid  = blockIdx.x;
    const int side = bid >> 8;
    const int b    = bid & 255;

    const int* ids  = side ? Iids : Uids;
    const int* docs = side ? Idocs : Udocs;

    const int uid = ids[b];
    const int* doc = docs + (long)uid * LL;

    // ---- phase 1: all 50 channels per thread, registers only ----
    float acc[NA * H1];
    #pragma unroll
    for (int c = 0; c < NA * H1; ++c) acc[c] = 0.f;

    if (tid < LL) {
        const int tok = doc[tid];                       // coalesced direct read
        const float4* e4 = (const float4*)(Wemb + (long)tok * DD);
        float4 e0 = e4[0];
        float4 e1 = e4[1];
        for (int db = 0; db < 75; ++db) {
            float4 e2 = e1;
            if (db < 73) e2 = e4[db + 2];               // 2-deep prefetch
            const float ev0 = e0.x, ev1 = e0.y, ev2 = e0.z, ev3 = e0.w;
            const int d0 = db * 4;
            #pragma unroll
            for (int a_ = 0; a_ < NA; ++a_) {
                const float* wp = AP + a_ * (DD * H1) + d0 * H1;  // uniform -> s_load
                #pragma unroll
                for (int h = 0; h < H1; ++h) {
                    acc[a_ * H1 + h] += ev0 * wp[h] + ev1 * wp[H1 + h]
                                      + ev2 * wp[2 * H1 + h] + ev3 * wp[3 * H1 + h];
                }
            }
            e0 = e1; e1 = e2;
        }
    }

    // ---- phase 2: one aspect at a time through LDS (round-9 verbatim) ----
    #pragma unroll
    for (int a_ = 0; a_ < NA; ++a_) {
        if (tid < LL) {
            #pragma unroll
            for (int h = 0; h < H1; ++h) adoc[tid][h] = acc[a_ * H1 + h];
        }
        __syncthreads();

        // window logits (round-9 exact chain)
        if (tid < LL) {
            const float* aerow = AE + a_ * 30;       // uniform -> s_load
            float s = 0.f;
            if (tid > 0) {
                const float* ad = &adoc[tid - 1][0];
                #pragma unroll
                for (int h = 0; h < H1; ++h) s += ad[h] * aerow[h];
            }
            {
                const float* ad = &adoc[tid][0];
                #pragma unroll
                for (int h = 0; h < H1; ++h) s += ad[h] * aerow[H1 + h];
            }
            if (tid < LL - 1) {
                const float* ad = &adoc[tid + 1][0];
                #pragma unroll
                for (int h = 0; h < H1; ++h) s += ad[h] * aerow[2 * H1 + h];
            }
            lg[tid] = s;
        }
        __syncthreads();

        // softmax over L + weighted sum (wave 0; round-9 exact reduction)
        if (tid < 64) {
            const int lane = tid;
            float mx = -1e30f;
            for (int p = lane; p < LL; p += 64) mx = fmaxf(mx, lg[p]);
            #pragma unroll
            for (int o = 32; o; o >>= 1) mx = fmaxf(mx, __shfl_xor(mx, o, 64));
            float sum = 0.f;
            for (int p = lane; p < LL; p += 64) {
                float pr = expf(lg[p] - mx);
                lg[p] = pr;
                sum += pr;
            }
            #pragma unroll
            for (int o = 32; o; o >>= 1) sum += __shfl_xor(sum, o, 64);
            float r[H1];
            #pragma unroll
            for (int h = 0; h < H1; ++h) r[h] = 0.f;
            for (int p = lane; p < LL; p += 64) {
                const float pr = lg[p];
                const float* ad = &adoc[p][0];
                #pragma unroll
                for (int h = 0; h < H1; ++h) r[h] += pr * ad[h];
            }
            #pragma unroll
            for (int h = 0; h < H1; ++h) {
                #pragma unroll
                for (int o = 32; o; o >>= 1) r[h] += __shfl_xor(r[h], o, 64);
            }
            if (lane == 0) {
                const float inv = 1.f / sum;
                float* out = Rep + (((long)side * NB + b) * NA + a_) * H1;
                #pragma unroll
                for (int h = 0; h < H1; ++h) out[h] = r[h] * inv;
            }
        }
        __syncthreads();   // adoc/lg reused next aspect
    }
}

__global__ __launch_bounds__(64)
void k_final(const float* __restrict__ Rep, const int* __restrict__ Uids,
             const int* __restrict__ Iids, const float* __restrict__ M,
             const float* __restrict__ Uproj, const float* __restrict__ Uw,
             const float* __restrict__ Iproj, const float* __restrict__ Iw,
             const float* __restrict__ Bu, const float* __restrict__ Bi,
             const float* __restrict__ Bg, float* __restrict__ out)
{
    __shared__ float Ud[50], Idd[50], tmp[50], aff[25];
    const int b = blockIdx.x, lane = threadIdx.x;
    if (lane < 50) {
        Ud[lane]  = Rep[(long)b * 50 + lane];
        Idd[lane] = Rep[(long)NB * 50 + (long)b * 50 + lane];
    }
    __syncthreads();
    if (lane < 50) {  // tmp[c][h] = sum_k M[h][k] * Id[c][k]
        const int c = lane / 10, h = lane % 10;
        float t = 0.f;
        #pragma unroll
        for (int k = 0; k < 10; ++k) t += M[h * 10 + k] * Idd[c * 10 + k];
        tmp[lane] = t;
    }
    __syncthreads();
    if (lane < 25) {  // aff[a][c] = relu(sum_h Ud[a][h] * tmp[c][h])
        const int a_ = lane / 5, c = lane % 5;
        float s = 0.f;
        #pragma unroll
        for (int h = 0; h < 10; ++h) s += Ud[a_ * 10 + h] * tmp[c * 10 + h];
        aff[lane] = fmaxf(s, 0.f);
    }
    __syncthreads();

    float hu1[5], hi1[5], tu[5], ti[5];
    if (lane < 50) {
        #pragma unroll
        for (int a_ = 0; a_ < 5; ++a_) {
            float su = 0.f, si = 0.f;
            #pragma unroll
            for (int h = 0; h < 10; ++h) {
                su += Uproj[lane * 10 + h] * Ud[a_ * 10 + h];
                si += Iproj[lane * 10 + h] * Idd[a_ * 10 + h];
            }
            hu1[a_] = su; hi1[a_] = si;
        }
    } else {
        #pragma unroll
        for (int a_ = 0; a_ < 5; ++a_) { hu1[a_] = 0.f; hi1[a_] = 0.f; }
    }
    const float uw = (lane < 50) ? Uw[lane] : 0.f;
    const float iw = (lane < 50) ? Iw[lane] : 0.f;
    #pragma unroll
    for (int a_ = 0; a_ < 5; ++a_) {
        float hu = hu1[a_], hi = hi1[a_];
        #pragma unroll
        for (int c = 0; c < 5; ++c) {
            hu += hi1[c] * aff[a_ * 5 + c];   // Hu[e][a] += Hi1[e][c]*aff[a][c]
            hi += hu1[c] * aff[c * 5 + a_];   // Hi[e][c] += Hu1[e][a]*aff[a][c]
        }
        tu[a_] = uw * fmaxf(hu, 0.f);
        ti[a_] = iw * fmaxf(hi, 0.f);
    }
    #pragma unroll
    for (int a_ = 0; a_ < 5; ++a_) {
        #pragma unroll
        for (int o = 32; o; o >>= 1) {
            tu[a_] += __shfl_xor(tu[a_], o, 64);
            ti[a_] += __shfl_xor(ti[a_], o, 64);
        }
    }
    if (lane == 0) {
        float mu = tu[0], mi = ti[0];
        #pragma unroll
        for (int a_ = 1; a_ < 5; ++a_) { mu = fmaxf(mu, tu[a_]); mi = fmaxf(mi, ti[a_]); }
        float eu[5], ei[5], su = 0.f, si = 0.f;
        #pragma unroll
        for (int a_ = 0; a_ < 5; ++a_) {
            eu[a_] = expf(tu[a_] - mu); su += eu[a_];
            ei[a_] = expf(ti[a_] - mi); si += ei[a_];
        }
        float R = 0.f;
        #pragma unroll
        for (int a_ = 0; a_ < 5; ++a_) {
            float ar = 0.f;
            #pragma unroll
            for (int h = 0; h < 10; ++h) ar += Ud[a_ * 10 + h] * Idd[a_ * 10 + h];
            R += (eu[a_] / su) * (ei[a_] / si) * ar;
        }
        R += Bu[Uids[b]] + Bi[Iids[b]] + Bg[0];
        out[b] = R;
    }
}

extern "C" void kernel_launch(void* const* d_in, const int* in_sizes, int n_in,
                              void* d_out, int out_size, void* d_ws, size_t ws_size,
                              hipStream_t stream)
{
    const int*   Uids  = (const int*)d_in[0];
    const int*   Iids  = (const int*)d_in[1];
    const int*   Udocs = (const int*)d_in[2];
    const int*   Idocs = (const int*)d_in[3];
    const float* Wemb  = (const float*)d_in[4];
    const float* AE    = (const float*)d_in[5];
    const float* AP    = (const float*)d_in[6];
    const float* M     = (const float*)d_in[7];
    const float* Uproj = (const float*)d_in[8];
    const float* Uw    = (const float*)d_in[9];
    const float* Iproj = (const float*)d_in[10];
    const float* Iw    = (const float*)d_in[11];
    const float* Bu    = (const float*)d_in[12];
    const float* Bi    = (const float*)d_in[13];
    const float* Bg    = (const float*)d_in[14];

    float* Rep = (float*)d_ws;        // [2][256][5][10] = 102400 B
    float* out = (float*)d_out;

    k_aspect<<<2 * NB, 512, 0, stream>>>(Uids, Iids, Udocs, Idocs, Wemb, AE, AP, Rep);
    k_final<<<NB, 64, 0, stream>>>(Rep, Uids, Iids, M, Uproj, Uw, Iproj, Iw, Bu, Bi, Bg, out);
}